// Round 15
// baseline (544.700 us; speedup 1.0000x reference)
//
#include <hip/hip_runtime.h>
#include <hip/hip_bf16.h>
#include <math.h>

#define B_DIM 512
#define E_DIM 512
#define W_DIM 64
#define V_DIM 32000
#define H_DIM 5120

typedef short bf16x8 __attribute__((ext_vector_type(8)));
typedef float f32x4 __attribute__((ext_vector_type(4)));

// RNE f32->bf16 pair pack; compiler emits v_cvt_pk_bf16_f32 on gfx950.
static __device__ __forceinline__ unsigned pk2(float a, float b) {
  union { __hip_bfloat16 h; unsigned short u; } ca, cb;
  ca.h = __float2bfloat16(a);
  cb.h = __float2bfloat16(b);
  return (unsigned)ca.u | ((unsigned)cb.u << 16);
}
static __device__ __forceinline__ unsigned short f2b(float a) {
  union { __hip_bfloat16 h; unsigned short u; } c;
  c.h = __float2bfloat16(a);
  return c.u;
}

// ---------------- Attention: one block per batch row ----------------
__global__ __launch_bounds__(256) void attn_kernel(
    const float* __restrict__ state, const float* __restrict__ encode,
    const float* __restrict__ aW1, const float* __restrict__ aW2,
    const float* __restrict__ aW3, float* __restrict__ ctx) {
  const int b = blockIdx.x;
  const int tid = threadIdx.x;
  __shared__ float rq[512];
  __shared__ float sc[64];
  rq[tid]       = state[(size_t)b * 512 + tid]       * aW1[tid];
  rq[tid + 256] = state[(size_t)b * 512 + tid + 256] * aW1[tid + 256];
  __syncthreads();
  const int lane = tid & 63, wv = tid >> 6;
  const float* enc = encode + (size_t)b * 64 * 512;
  for (int w = wv; w < 64; w += 4) {
    const float* er  = enc + w * 512;
    const float* w2r = aW2 + w * 512;
    const float* w3r = aW3 + w * 512;
    float s = 0.f;
#pragma unroll
    for (int k = 0; k < 8; ++k) {
      int e = lane + k * 64;
      s += tanhf(rq[e] * er[e] * w2r[e]) * w3r[e];
    }
#pragma unroll
    for (int o = 32; o; o >>= 1) s += __shfl_xor(s, o, 64);
    if (lane == 0) sc[w] = s;
  }
  __syncthreads();
  if (tid < 64) {
    float v = sc[tid];
    float mx = v;
#pragma unroll
    for (int o = 32; o; o >>= 1) mx = fmaxf(mx, __shfl_xor(mx, o, 64));
    float e = __expf(v - mx);
    float sm = e;
#pragma unroll
    for (int o = 32; o; o >>= 1) sm += __shfl_xor(sm, o, 64);
    sc[tid] = e / sm;
  }
  __syncthreads();
  for (int e = tid; e < 512; e += 256) {
    float acc = 0.f;
#pragma unroll 8
    for (int w = 0; w < 64; ++w) acc += sc[w] * enc[w * 512 + e];
    ctx[(size_t)b * 512 + e] = acc;
  }
}

// ---------------- pack three -> bf16 concat [512][1536] ----------------
__global__ __launch_bounds__(256) void pack3b(
    const float* __restrict__ s0, const float* __restrict__ s1,
    const float* __restrict__ s2, unsigned short* __restrict__ dst) {
  const int s = blockIdx.y;
  const int i = blockIdx.x * 256 + threadIdx.x;
  const float* src = (s == 0) ? s0 : ((s == 1) ? s1 : s2);
  const int b = i >> 9, e = i & 511;
  dst[(size_t)b * 1536 + s * 512 + e] = f2b(src[i]);
}

// ---------------- GRU gate math (XP x-partials, RP r-partials) ----------------
template <int XP, int RP>
__global__ __launch_bounds__(256) void gru_gate(
    const float* __restrict__ X, const float* __restrict__ bi,
    const float* __restrict__ R, const float* __restrict__ br,
    const float* __restrict__ hprev, float* __restrict__ hout) {
  const int i = blockIdx.x * 256 + threadIdx.x;  // 0..262143
  const int b = i >> 9, e = i & 511;
  const float* Xr = X + (size_t)b * 1536;
  float xz = bi[e], xr = bi[512 + e], xh = bi[1024 + e];
#pragma unroll
  for (int p = 0; p < XP; ++p) {
    const float* Xp = Xr + (size_t)p * 2359296;  // 1536*1536
    xz += Xp[e]; xr += Xp[512 + e]; xh += Xp[1024 + e];
  }
  float rz = br[e], rr = br[512 + e], rh = br[1024 + e];
  if (RP > 0) {
    const float* Rr = R + (size_t)b * 1536;
#pragma unroll
    for (int p = 0; p < RP; ++p) {
      const float* Rp = Rr + (size_t)p * 786432;  // 512*1536
      rz += Rp[e]; rr += Rp[512 + e]; rh += Rp[1024 + e];
    }
  }
  const float h = hprev ? hprev[i] : 0.f;
  const float z = 1.f / (1.f + __expf(-(xz + rz)));
  const float r = 1.f / (1.f + __expf(-(xr + rr)));
  const float hh = tanhf(xh + r * rh);
  hout[i] = z * h + (1.f - z) * hh;
}

// ---------------- small-M bf16 MFMA GEMM (GRU path) ----------------
template <int PARTS>
__global__ __launch_bounds__(256, 2) void gemm_k(
    const float* __restrict__ a0, const float* __restrict__ a1,
    const float* __restrict__ a2, const float* __restrict__ B,
    float* __restrict__ C, int M, int N, int K) {
  __shared__ unsigned short As[128 * 72];
  __shared__ unsigned short Bs[128 * 72];
  const int tid = threadIdx.x;
  const int bid = blockIdx.x;
  const int tiles_m = M >> 7;
  const int mt = bid % tiles_m;
  const int nt = bid / tiles_m;
  const long m0 = (long)mt * 128, n0 = (long)nt * 128;
  const int Kp = K / PARTS;
  const int k0 = blockIdx.y * Kp;

  const int a_m = tid & 127;
  const int a_h = tid >> 7;
  unsigned short* awp = As + a_m * 72 + a_h * 32;
  const int b_n = (tid & 31) << 2;
  const int b_q = (tid >> 5) & 3;
  const int b_h = tid >> 7;
  const int b_sw = ((b_q ^ (tid & 3)) << 3) + b_h * 32;

  const int lane = tid & 63;
  const int wid = tid >> 6;
  const int wm = (wid >> 1) << 6, wn = (wid & 1) << 6;
  const int lr = lane & 15, lg = lane >> 4;

  int aro[4], bro[4];
#pragma unroll
  for (int i = 0; i < 4; ++i)
    aro[i] = (wm + 16 * i + lr) * 72 + 8 * lg;
#pragma unroll
  for (int j = 0; j < 4; ++j) {
    const int n = wn + 16 * j + lr;
    bro[j] = n * 72 + 8 * (lg ^ ((n >> 2) & 3));
  }

  f32x4 acc[4][4];
#pragma unroll
  for (int i = 0; i < 4; ++i)
#pragma unroll
    for (int j = 0; j < 4; ++j) acc[i][j] = f32x4{0.f, 0.f, 0.f, 0.f};

  const int row = (int)m0 + a_m;
  const float* asrc = (row < 512) ? a0 : ((row < 1024) ? a1 : a2);
  const float* ap = asrc + (size_t)(row & 511) * 512 + k0 + a_h * 32;
  const float* bp = B + (size_t)(k0 + b_h * 32 + b_q * 8) * N + n0 + b_n;

  float4 pb[8];
#pragma unroll
  for (int j = 0; j < 8; ++j) pb[j] = *(const float4*)(bp + (size_t)j * N);
  bp += (size_t)64 * N;

  const int nsteps = Kp >> 6;
  for (int t = 0; t < nsteps; ++t) {
    float4 pa[8];
#pragma unroll
    for (int j = 0; j < 8; ++j) pa[j] = *(const float4*)(ap + 4 * j);
    ap += 64;
    {
      uint4 w;
      w.x = pk2(pb[0].x, pb[1].x); w.y = pk2(pb[2].x, pb[3].x);
      w.z = pk2(pb[4].x, pb[5].x); w.w = pk2(pb[6].x, pb[7].x);
      *(uint4*)(Bs + (b_n + 0) * 72 + b_sw) = w;
      w.x = pk2(pb[0].y, pb[1].y); w.y = pk2(pb[2].y, pb[3].y);
      w.z = pk2(pb[4].y, pb[5].y); w.w = pk2(pb[6].y, pb[7].y);
      *(uint4*)(Bs + (b_n + 1) * 72 + b_sw) = w;
      w.x = pk2(pb[0].z, pb[1].z); w.y = pk2(pb[2].z, pb[3].z);
      w.z = pk2(pb[4].z, pb[5].z); w.w = pk2(pb[6].z, pb[7].z);
      *(uint4*)(Bs + (b_n + 2) * 72 + b_sw) = w;
      w.x = pk2(pb[0].w, pb[1].w); w.y = pk2(pb[2].w, pb[3].w);
      w.z = pk2(pb[4].w, pb[5].w); w.w = pk2(pb[6].w, pb[7].w);
      *(uint4*)(Bs + (b_n + 3) * 72 + b_sw) = w;
    }
#pragma unroll
    for (int c = 0; c < 4; ++c) {
      uint4 w;
      w.x = pk2(pa[2 * c].x, pa[2 * c].y);
      w.y = pk2(pa[2 * c].z, pa[2 * c].w);
      w.z = pk2(pa[2 * c + 1].x, pa[2 * c + 1].y);
      w.w = pk2(pa[2 * c + 1].z, pa[2 * c + 1].w);
      *(uint4*)(awp + 8 * c) = w;
    }
    __syncthreads();
    if (t + 1 < nsteps) {
#pragma unroll
      for (int j = 0; j < 8; ++j) pb[j] = *(const float4*)(bp + (size_t)j * N);
      bp += (size_t)64 * N;
    }
#pragma unroll
    for (int s = 0; s < 2; ++s) {
      bf16x8 af[4], bfr[4];
#pragma unroll
      for (int i = 0; i < 4; ++i)
        af[i] = *(const bf16x8*)(As + aro[i] + 32 * s);
#pragma unroll
      for (int j = 0; j < 4; ++j)
        bfr[j] = *(const bf16x8*)(Bs + bro[j] + 32 * s);
#pragma unroll
      for (int i = 0; i < 4; ++i)
#pragma unroll
        for (int j = 0; j < 4; ++j)
          acc[i][j] = __builtin_amdgcn_mfma_f32_16x16x32_bf16(af[i], bfr[j], acc[i][j], 0, 0, 0);
    }
    __syncthreads();
  }
  float* Cp = (PARTS > 1) ? (C + (size_t)blockIdx.y * M * (size_t)N) : C;
#pragma unroll
  for (int j = 0; j < 4; ++j) {
    const long col = n0 + wn + j * 16 + lr;
#pragma unroll
    for (int i = 0; i < 4; ++i) {
      const long row2 = m0 + wm + i * 16 + (lg << 2);
#pragma unroll
      for (int r = 0; r < 4; ++r)
        Cp[(row2 + r) * N + col] = acc[i][j][r];
    }
  }
}

// ---------------- 128-col panel GEMM: proven round-9/10/12 kernel ----------------
// One block per 128-col panel covers ALL 512 rows -> B read exactly once.
// A16 bf16 frags direct from global; single af set; half-set reloads land a
// full subtile+barrier before use (window discipline, r11/r13 lesson).
template <int ACT, int PARTS>
__global__ __launch_bounds__(512, 2) void gemm_pn(
    const unsigned short* __restrict__ A16, const float* __restrict__ B,
    const float* __restrict__ bias, float* __restrict__ C,
    int N, int K) {
  __shared__ unsigned short Bs[2][128 * 72];
  const int tid = threadIdx.x;
  const long n0 = (long)blockIdx.x * 128;
  const int Kp = K / PARTS;
  const int k0 = blockIdx.y * Kp;

  const int b_x = tid & 31;
  const int b_n = b_x << 2;
  const int b_g = tid >> 5;  // 0..15
  const int b_gs = (((b_g >> 1) ^ ((b_x >> 1) & 7)) << 1) | (b_g & 1);
  const int bw0 = (b_n + 0) * 72 + b_gs * 4;
  const int bw1 = (b_n + 1) * 72 + b_gs * 4;
  const int bw2 = (b_n + 2) * 72 + b_gs * 4;
  const int bw3 = (b_n + 3) * 72 + b_gs * 4;

  const int lane = tid & 63;
  const int wid = tid >> 6;
  const int wm = wid << 6;
  const int lr = lane & 15, lg = lane >> 4;

  int bbase[8], bslot[8];
#pragma unroll
  for (int j = 0; j < 8; ++j) {
    const int n = 16 * j + lr;
    bbase[j] = n * 72;
    bslot[j] = lg ^ ((n >> 3) & 7);
  }

  f32x4 acc[4][8];
#pragma unroll
  for (int i = 0; i < 4; ++i)
#pragma unroll
    for (int j = 0; j < 8; ++j) acc[i][j] = f32x4{0.f, 0.f, 0.f, 0.f};

  const unsigned short* ap0 = A16 + (size_t)(wm + lr) * K + k0 + 8 * lg;
  const unsigned short* ap1 = ap0 + (size_t)16 * K;
  const unsigned short* ap2 = ap0 + (size_t)32 * K;
  const unsigned short* ap3 = ap0 + (size_t)48 * K;
  const float* bp = B + (size_t)(k0 + b_g * 4) * N + n0 + b_n;

  float4 pb0, pb1, pb2, pb3;
  bf16x8 af[8];

#define LOAD_B()                                  \
  do {                                            \
    pb0 = *(const float4*)(bp);                   \
    pb1 = *(const float4*)(bp + N);               \
    pb2 = *(const float4*)(bp + 2 * (size_t)N);   \
    pb3 = *(const float4*)(bp + 3 * (size_t)N);   \
    bp += (size_t)64 * N;                         \
  } while (0)

#define LOAD_A0()                                 \
  do {                                            \
    af[0] = *(const bf16x8*)(ap0);                \
    af[1] = *(const bf16x8*)(ap1);                \
    af[2] = *(const bf16x8*)(ap2);                \
    af[3] = *(const bf16x8*)(ap3);                \
  } while (0)

#define LOAD_A1()                                 \
  do {                                            \
    af[4] = *(const bf16x8*)(ap0 + 32);           \
    af[5] = *(const bf16x8*)(ap1 + 32);           \
    af[6] = *(const bf16x8*)(ap2 + 32);           \
    af[7] = *(const bf16x8*)(ap3 + 32);           \
    ap0 += 64; ap1 += 64; ap2 += 64; ap3 += 64;   \
  } while (0)

#define WRITE_B(buf)                                           \
  do {                                                         \
    uint2 qv;                                                  \
    qv.x = pk2(pb0.x, pb1.x); qv.y = pk2(pb2.x, pb3.x);        \
    *(uint2*)(Bs[buf] + bw0) = qv;                             \
    qv.x = pk2(pb0.y, pb1.y); qv.y = pk2(pb2.y, pb3.y);        \
    *(uint2*)(Bs[buf] + bw1) = qv;                             \
    qv.x = pk2(pb0.z, pb1.z); qv.y = pk2(pb2.z, pb3.z);        \
    *(uint2*)(Bs[buf] + bw2) = qv;                             \
    qv.x = pk2(pb0.w, pb1.w); qv.y = pk2(pb2.w, pb3.w);        \
    *(uint2*)(Bs[buf] + bw3) = qv;                             \
  } while (0)

  const int nsteps = Kp >> 6;
  LOAD_B();
  LOAD_A0();
  LOAD_A1();
  WRITE_B(0);
  LOAD_B();
  asm volatile("s_waitcnt lgkmcnt(0)" ::: "memory");
  __builtin_amdgcn_s_barrier();

  for (int t = 0; t < nsteps; ++t) {
    const int buf = t & 1;
    if (t + 1 < nsteps) { WRITE_B(buf ^ 1); }
    if (t + 2 < nsteps) { LOAD_B(); }
    {
      bf16x8 bfr[8];
#pragma unroll
      for (int j = 0; j < 8; ++j)
        bfr[j] = *(const bf16x8*)(Bs[buf] + bbase[j] + 8 * bslot[j]);
#pragma unroll
      for (int i = 0; i < 4; ++i)
#pragma unroll
        for (int j = 0; j < 8; ++j)
          acc[i][j] = __builtin_amdgcn_mfma_f32_16x16x32_bf16(
              af[i], bfr[j], acc[i][j], 0, 0, 0);
    }
    if (t + 1 < nsteps) { LOAD_A0(); }
    {
      bf16x8 bfr[8];
#pragma unroll
      for (int j = 0; j < 8; ++j)
        bfr[j] = *(const bf16x8*)(Bs[buf] + bbase[j] + 8 * (bslot[j] ^ 4));
#pragma unroll
      for (int i = 0; i < 4; ++i)
#pragma unroll
        for (int j = 0; j < 8; ++j)
          acc[i][j] = __builtin_amdgcn_mfma_f32_16x16x32_bf16(
              af[4 + i], bfr[j], acc[i][j], 0, 0, 0);
    }
    if (t + 1 < nsteps) { LOAD_A1(); }
    asm volatile("s_waitcnt lgkmcnt(0)" ::: "memory");
    __builtin_amdgcn_s_barrier();
  }
#undef LOAD_B
#undef LOAD_A0
#undef LOAD_A1
#undef WRITE_B
  float* Cp = (PARTS > 1) ? (C + (size_t)blockIdx.y * 512 * (size_t)N) : C;
#pragma unroll
  for (int j = 0; j < 8; ++j) {
    const long col = n0 + 16 * j + lr;
    const float bv = (PARTS == 1 && bias) ? bias[col] : 0.f;
#pragma unroll
    for (int i = 0; i < 4; ++i) {
      const long row = wm + 16 * i + (lg << 2);
#pragma unroll
      for (int r = 0; r < 4; ++r) {
        float x = acc[i][j][r] + bv;
        if (PARTS == 1 && ACT == 1) x = tanhf(x);
        Cp[(row + r) * N + col] = x;
      }
    }
  }
}

// ---------------- split-K reduce: dst = act(sum_p P[p] + bias), bf16 out ----------------
template <int ACT, int PARTS>
__global__ __launch_bounds__(256) void reduce_parts_b(
    const float* __restrict__ P, const float* __restrict__ bias,
    unsigned short* __restrict__ dst, int N) {
  const int col = blockIdx.x * 256 + threadIdx.x;
  const int row = blockIdx.y;
  const size_t MN = (size_t)512 * N;
  const size_t idx = (size_t)row * N + col;
  float s = bias[col];
#pragma unroll
  for (int p = 0; p < PARTS; ++p) s += P[p * MN + idx];
  dst[idx] = f2b((ACT == 1) ? tanhf(s) : s);
}

// ---------------- fused softmax over 2 logits partials + bias ----------------
// probs[b][:] = softmax(P0[b][:] + P1[b][:] + bias), 2-pass online.
__global__ __launch_bounds__(256) void softmax_fused(
    const float* __restrict__ P0, const float* __restrict__ P1,
    const float* __restrict__ bias, float* __restrict__ outp) {
  const int b = blockIdx.x;
  const int tid = threadIdx.x;
  const int lane = tid & 63, w = tid >> 6;
  __shared__ float sm[4], sl[4];
  const float4* r0 = (const float4*)(P0 + (size_t)b * V_DIM);
  const float4* r1 = (const float4*)(P1 + (size_t)b * V_DIM);
  const float4* b4 = (const float4*)bias;
  float4* w4p = (float4*)(outp + (size_t)b * V_DIM);
  float m = -3.4e38f, l = 0.f;
  for (int i = tid; i < V_DIM / 4; i += 256) {
    float4 a = r0[i], c = r1[i], d = b4[i];
    float4 v;
    v.x = a.x + c.x + d.x; v.y = a.y + c.y + d.y;
    v.z = a.z + c.z + d.z; v.w = a.w + c.w + d.w;
    float cm = fmaxf(fmaxf(v.x, v.y), fmaxf(v.z, v.w));
    if (cm > m) { l *= __expf(m - cm); m = cm; }
    l += __expf(v.x - m) + __expf(v.y - m) + __expf(v.z - m) + __expf(v.w - m);
  }
#pragma unroll
  for (int o = 32; o; o >>= 1) {
    float om = __shfl_xor(m, o, 64);
    float ol = __shfl_xor(l, o, 64);
    float nm = fmaxf(m, om);
    l = l * __expf(m - nm) + ol * __expf(om - nm);
    m = nm;
  }
  if (lane == 0) { sm[w] = m; sl[w] = l; }
  __syncthreads();
  float M = fmaxf(fmaxf(sm[0], sm[1]), fmaxf(sm[2], sm[3]));
  float L = sl[0] * __expf(sm[0] - M) + sl[1] * __expf(sm[1] - M) +
            sl[2] * __expf(sm[2] - M) + sl[3] * __expf(sm[3] - M);
  const float inv = 1.f / L;
  for (int i = tid; i < V_DIM / 4; i += 256) {
    float4 a = r0[i], c = r1[i], d = b4[i];
    float4 o4;
    o4.x = __expf(a.x + c.x + d.x - M) * inv;
    o4.y = __expf(a.y + c.y + d.y - M) * inv;
    o4.z = __expf(a.z + c.z + d.z - M) * inv;
    o4.w = __expf(a.w + c.w + d.w - M) * inv;
    w4p[i] = o4;
  }
}

extern "C" void kernel_launch(void* const* d_in, const int* in_sizes, int n_in,
                              void* d_out, int out_size, void* d_ws, size_t ws_size,
                              hipStream_t stream) {
  const float* y      = (const float*)d_in[0];
  const float* state  = (const float*)d_in[1];
  const float* encode = (const float*)d_in[2];
  const float* aW1    = (const float*)d_in[3];
  const float* aW2    = (const float*)d_in[4];
  const float* aW3    = (const float*)d_in[5];
  const float* gk     = (const float*)d_in[6];
  const float* grk    = (const float*)d_in[7];
  const float* gb     = (const float*)d_in[8];
  const float* w1     = (const float*)d_in[9];
  const float* b1     = (const float*)d_in[10];
  const float* w2     = (const float*)d_in[11];
  const float* b2     = (const float*)d_in[12];
  const float* w3     = (const float*)d_in[13];
  const float* b3     = (const float*)d_in[14];
  float* out = (float*)d_out;
  float* ws = (float*)d_ws;

  float* ctx = ws;                            // 262144 f32
  float* X0  = ws + 262144;                   // 4 x 2359296 f32 (Xall partials)
  float* R0  = ws + 9699328;                  // 4 x 786432 f32 (R partials)
  float* hg1 = ws + 12845056;                 // 262144 f32
  float* hg2 = ws + 13107200;                 // 262144 f32
  unsigned short* gb16 = (unsigned short*)(ws + 13369344);  // 512*1536 bf16
  unsigned short* dd1b = (unsigned short*)(ws + 13762560);  // 512*5120 bf16
  unsigned short* dd2b = (unsigned short*)(ws + 15073280);  // 512*5120 bf16
  float* PL = ws + 16777216;                  // 2 x 16384000 f32 logits partials

  float* g_out = out;                               // [512, 32000]
  float* h3 = out + (size_t)B_DIM * V_DIM;          // new_state [512, 512]
  float* P = out;  // w1/w2 split-K partials in not-yet-written logits region
                   // (max 6 * 512*5120 f32 = 63 MB < 65.5 MB)

  const float* bi = gb;
  const float* br = gb + 1536;

  attn_kernel<<<512, 256, 0, stream>>>(state, encode, aW1, aW2, aW3, ctx);
  // Xall = [state;ctx;y] @ gk (seq-stack fused), split-K=4
  gemm_k<4><<<dim3(12 * 12, 4), 256, 0, stream>>>(state, ctx, y, gk, X0, 1536, 1536, 512);
  gru_gate<4, 0><<<1024, 256, 0, stream>>>(X0, bi, nullptr, br, nullptr, hg1);
  gemm_k<4><<<dim3(4 * 12, 4), 256, 0, stream>>>(hg1, hg1, hg1, grk, R0, 512, 1536, 512);
  gru_gate<4, 4><<<1024, 256, 0, stream>>>(X0 + 786432, bi, R0, br, hg1, hg2);
  gemm_k<4><<<dim3(4 * 12, 4), 256, 0, stream>>>(hg2, hg2, hg2, grk, R0, 512, 1536, 512);
  gru_gate<4, 4><<<1024, 256, 0, stream>>>(X0 + 1572864, bi, R0, br, hg2, h3);
  // g = [y | ctx | new_state] as bf16
  pack3b<<<dim3(1024, 3), 256, 0, stream>>>(y, ctx, h3, gb16);
  // h1 = tanh(g@w1+b1): 128-panel, split-K=6
  gemm_pn<0, 6><<<dim3(40, 6), 512, 0, stream>>>(gb16, w1, nullptr, P, H_DIM, 1536);
  reduce_parts_b<1, 6><<<dim3(20, 512), 256, 0, stream>>>(P, b1, dd1b, H_DIM);
  // h2 = tanh(h1@w2+b2): 128-panel, split-K=5
  gemm_pn<0, 5><<<dim3(40, 5), 512, 0, stream>>>(dd1b, w2, nullptr, P, H_DIM, H_DIM);
  reduce_parts_b<1, 5><<<dim3(20, 512), 256, 0, stream>>>(P, b2, dd2b, H_DIM);
  // logits partials: split-K=2 -> 500 blocks = 2 INDEPENDENT barrier groups
  // per CU (r13 lesson: occupancy helps only as independent phase groups).
  // B traffic unchanged (each block reads its K-half of w3 once).
  gemm_pn<0, 2><<<dim3(250, 2), 512, 0, stream>>>(dd2b, w3, nullptr, PL, V_DIM, H_DIM);
  // softmax fuses partial-sum + bias (one extra 65MB read per pass)
  softmax_fused<<<512, 256, 0, stream>>>(PL, PL + (size_t)512 * V_DIM, b3, g_out);
}

// Round 16
// 517.982 us; speedup vs baseline: 1.0516x; 1.0516x over previous
//
#include <hip/hip_runtime.h>
#include <hip/hip_bf16.h>
#include <math.h>

#define B_DIM 512
#define E_DIM 512
#define W_DIM 64
#define V_DIM 32000
#define H_DIM 5120

typedef short bf16x8 __attribute__((ext_vector_type(8)));
typedef float f32x4 __attribute__((ext_vector_type(4)));

// RNE f32->bf16 pair pack; compiler emits v_cvt_pk_bf16_f32 on gfx950.
static __device__ __forceinline__ unsigned pk2(float a, float b) {
  union { __hip_bfloat16 h; unsigned short u; } ca, cb;
  ca.h = __float2bfloat16(a);
  cb.h = __float2bfloat16(b);
  return (unsigned)ca.u | ((unsigned)cb.u << 16);
}
static __device__ __forceinline__ unsigned short f2b(float a) {
  union { __hip_bfloat16 h; unsigned short u; } c;
  c.h = __float2bfloat16(a);
  return c.u;
}

// ---------------- Attention: one block per batch row ----------------
__global__ __launch_bounds__(256) void attn_kernel(
    const float* __restrict__ state, const float* __restrict__ encode,
    const float* __restrict__ aW1, const float* __restrict__ aW2,
    const float* __restrict__ aW3, float* __restrict__ ctx) {
  const int b = blockIdx.x;
  const int tid = threadIdx.x;
  __shared__ float rq[512];
  __shared__ float sc[64];
  rq[tid]       = state[(size_t)b * 512 + tid]       * aW1[tid];
  rq[tid + 256] = state[(size_t)b * 512 + tid + 256] * aW1[tid + 256];
  __syncthreads();
  const int lane = tid & 63, wv = tid >> 6;
  const float* enc = encode + (size_t)b * 64 * 512;
  for (int w = wv; w < 64; w += 4) {
    const float* er  = enc + w * 512;
    const float* w2r = aW2 + w * 512;
    const float* w3r = aW3 + w * 512;
    float s = 0.f;
#pragma unroll
    for (int k = 0; k < 8; ++k) {
      int e = lane + k * 64;
      s += tanhf(rq[e] * er[e] * w2r[e]) * w3r[e];
    }
#pragma unroll
    for (int o = 32; o; o >>= 1) s += __shfl_xor(s, o, 64);
    if (lane == 0) sc[w] = s;
  }
  __syncthreads();
  if (tid < 64) {
    float v = sc[tid];
    float mx = v;
#pragma unroll
    for (int o = 32; o; o >>= 1) mx = fmaxf(mx, __shfl_xor(mx, o, 64));
    float e = __expf(v - mx);
    float sm = e;
#pragma unroll
    for (int o = 32; o; o >>= 1) sm += __shfl_xor(sm, o, 64);
    sc[tid] = e / sm;
  }
  __syncthreads();
  for (int e = tid; e < 512; e += 256) {
    float acc = 0.f;
#pragma unroll 8
    for (int w = 0; w < 64; ++w) acc += sc[w] * enc[w * 512 + e];
    ctx[(size_t)b * 512 + e] = acc;
  }
}

// ---------------- pack three -> bf16 concat [512][1536] ----------------
__global__ __launch_bounds__(256) void pack3b(
    const float* __restrict__ s0, const float* __restrict__ s1,
    const float* __restrict__ s2, unsigned short* __restrict__ dst) {
  const int s = blockIdx.y;
  const int i = blockIdx.x * 256 + threadIdx.x;
  const float* src = (s == 0) ? s0 : ((s == 1) ? s1 : s2);
  const int b = i >> 9, e = i & 511;
  dst[(size_t)b * 1536 + s * 512 + e] = f2b(src[i]);
}

// ---------------- GRU gate math (XP x-partials, RP r-partials) ----------------
template <int XP, int RP>
__global__ __launch_bounds__(256) void gru_gate(
    const float* __restrict__ X, const float* __restrict__ bi,
    const float* __restrict__ R, const float* __restrict__ br,
    const float* __restrict__ hprev, float* __restrict__ hout) {
  const int i = blockIdx.x * 256 + threadIdx.x;  // 0..262143
  const int b = i >> 9, e = i & 511;
  const float* Xr = X + (size_t)b * 1536;
  float xz = bi[e], xr = bi[512 + e], xh = bi[1024 + e];
#pragma unroll
  for (int p = 0; p < XP; ++p) {
    const float* Xp = Xr + (size_t)p * 2359296;  // 1536*1536
    xz += Xp[e]; xr += Xp[512 + e]; xh += Xp[1024 + e];
  }
  float rz = br[e], rr = br[512 + e], rh = br[1024 + e];
  if (RP > 0) {
    const float* Rr = R + (size_t)b * 1536;
#pragma unroll
    for (int p = 0; p < RP; ++p) {
      const float* Rp = Rr + (size_t)p * 786432;  // 512*1536
      rz += Rp[e]; rr += Rp[512 + e]; rh += Rp[1024 + e];
    }
  }
  const float h = hprev ? hprev[i] : 0.f;
  const float z = 1.f / (1.f + __expf(-(xz + rz)));
  const float r = 1.f / (1.f + __expf(-(xr + rr)));
  const float hh = tanhf(xh + r * rh);
  hout[i] = z * h + (1.f - z) * hh;
}

// ---------------- small-M bf16 MFMA GEMM (GRU path) ----------------
template <int PARTS>
__global__ __launch_bounds__(256, 2) void gemm_k(
    const float* __restrict__ a0, const float* __restrict__ a1,
    const float* __restrict__ a2, const float* __restrict__ B,
    float* __restrict__ C, int M, int N, int K) {
  __shared__ unsigned short As[128 * 72];
  __shared__ unsigned short Bs[128 * 72];
  const int tid = threadIdx.x;
  const int bid = blockIdx.x;
  const int tiles_m = M >> 7;
  const int mt = bid % tiles_m;
  const int nt = bid / tiles_m;
  const long m0 = (long)mt * 128, n0 = (long)nt * 128;
  const int Kp = K / PARTS;
  const int k0 = blockIdx.y * Kp;

  const int a_m = tid & 127;
  const int a_h = tid >> 7;
  unsigned short* awp = As + a_m * 72 + a_h * 32;
  const int b_n = (tid & 31) << 2;
  const int b_q = (tid >> 5) & 3;
  const int b_h = tid >> 7;
  const int b_sw = ((b_q ^ (tid & 3)) << 3) + b_h * 32;

  const int lane = tid & 63;
  const int wid = tid >> 6;
  const int wm = (wid >> 1) << 6, wn = (wid & 1) << 6;
  const int lr = lane & 15, lg = lane >> 4;

  int aro[4], bro[4];
#pragma unroll
  for (int i = 0; i < 4; ++i)
    aro[i] = (wm + 16 * i + lr) * 72 + 8 * lg;
#pragma unroll
  for (int j = 0; j < 4; ++j) {
    const int n = wn + 16 * j + lr;
    bro[j] = n * 72 + 8 * (lg ^ ((n >> 2) & 3));
  }

  f32x4 acc[4][4];
#pragma unroll
  for (int i = 0; i < 4; ++i)
#pragma unroll
    for (int j = 0; j < 4; ++j) acc[i][j] = f32x4{0.f, 0.f, 0.f, 0.f};

  const int row = (int)m0 + a_m;
  const float* asrc = (row < 512) ? a0 : ((row < 1024) ? a1 : a2);
  const float* ap = asrc + (size_t)(row & 511) * 512 + k0 + a_h * 32;
  const float* bp = B + (size_t)(k0 + b_h * 32 + b_q * 8) * N + n0 + b_n;

  float4 pb[8];
#pragma unroll
  for (int j = 0; j < 8; ++j) pb[j] = *(const float4*)(bp + (size_t)j * N);
  bp += (size_t)64 * N;

  const int nsteps = Kp >> 6;
  for (int t = 0; t < nsteps; ++t) {
    float4 pa[8];
#pragma unroll
    for (int j = 0; j < 8; ++j) pa[j] = *(const float4*)(ap + 4 * j);
    ap += 64;
    {
      uint4 w;
      w.x = pk2(pb[0].x, pb[1].x); w.y = pk2(pb[2].x, pb[3].x);
      w.z = pk2(pb[4].x, pb[5].x); w.w = pk2(pb[6].x, pb[7].x);
      *(uint4*)(Bs + (b_n + 0) * 72 + b_sw) = w;
      w.x = pk2(pb[0].y, pb[1].y); w.y = pk2(pb[2].y, pb[3].y);
      w.z = pk2(pb[4].y, pb[5].y); w.w = pk2(pb[6].y, pb[7].y);
      *(uint4*)(Bs + (b_n + 1) * 72 + b_sw) = w;
      w.x = pk2(pb[0].z, pb[1].z); w.y = pk2(pb[2].z, pb[3].z);
      w.z = pk2(pb[4].z, pb[5].z); w.w = pk2(pb[6].z, pb[7].z);
      *(uint4*)(Bs + (b_n + 2) * 72 + b_sw) = w;
      w.x = pk2(pb[0].w, pb[1].w); w.y = pk2(pb[2].w, pb[3].w);
      w.z = pk2(pb[4].w, pb[5].w); w.w = pk2(pb[6].w, pb[7].w);
      *(uint4*)(Bs + (b_n + 3) * 72 + b_sw) = w;
    }
#pragma unroll
    for (int c = 0; c < 4; ++c) {
      uint4 w;
      w.x = pk2(pa[2 * c].x, pa[2 * c].y);
      w.y = pk2(pa[2 * c].z, pa[2 * c].w);
      w.z = pk2(pa[2 * c + 1].x, pa[2 * c + 1].y);
      w.w = pk2(pa[2 * c + 1].z, pa[2 * c + 1].w);
      *(uint4*)(awp + 8 * c) = w;
    }
    __syncthreads();
    if (t + 1 < nsteps) {
#pragma unroll
      for (int j = 0; j < 8; ++j) pb[j] = *(const float4*)(bp + (size_t)j * N);
      bp += (size_t)64 * N;
    }
#pragma unroll
    for (int s = 0; s < 2; ++s) {
      bf16x8 af[4], bfr[4];
#pragma unroll
      for (int i = 0; i < 4; ++i)
        af[i] = *(const bf16x8*)(As + aro[i] + 32 * s);
#pragma unroll
      for (int j = 0; j < 4; ++j)
        bfr[j] = *(const bf16x8*)(Bs + bro[j] + 32 * s);
#pragma unroll
      for (int i = 0; i < 4; ++i)
#pragma unroll
        for (int j = 0; j < 4; ++j)
          acc[i][j] = __builtin_amdgcn_mfma_f32_16x16x32_bf16(af[i], bfr[j], acc[i][j], 0, 0, 0);
    }
    __syncthreads();
  }
  float* Cp = (PARTS > 1) ? (C + (size_t)blockIdx.y * M * (size_t)N) : C;
#pragma unroll
  for (int j = 0; j < 4; ++j) {
    const long col = n0 + wn + j * 16 + lr;
#pragma unroll
    for (int i = 0; i < 4; ++i) {
      const long row2 = m0 + wm + i * 16 + (lg << 2);
#pragma unroll
      for (int r = 0; r < 4; ++r)
        Cp[(row2 + r) * N + col] = acc[i][j][r];
    }
  }
}

// ---------------- 128-col panel GEMM: proven round-9/10/12/14 kernel ----------------
// One block per 128-col panel covers ALL 512 rows -> B read exactly once
// (structural reuse, not cache-luck). A16 bf16 frags direct from global
// (L2-shared across lockstep blocks); single af set (two sets spill at the
// 256-VGPR cap, r8); half-set reloads land a full subtile+barrier before
// use (window discipline — r11/r13/r15: neither in-block occupancy nor
// split-K phase groups beat intact load->use windows at 2 waves/SIMD).
template <int ACT, int PARTS>
__global__ __launch_bounds__(512, 2) void gemm_pn(
    const unsigned short* __restrict__ A16, const float* __restrict__ B,
    const float* __restrict__ bias, float* __restrict__ C,
    int N, int K) {
  __shared__ unsigned short Bs[2][128 * 72];
  const int tid = threadIdx.x;
  const long n0 = (long)blockIdx.x * 128;
  const int Kp = K / PARTS;
  const int k0 = blockIdx.y * Kp;

  const int b_x = tid & 31;
  const int b_n = b_x << 2;
  const int b_g = tid >> 5;  // 0..15
  const int b_gs = (((b_g >> 1) ^ ((b_x >> 1) & 7)) << 1) | (b_g & 1);
  const int bw0 = (b_n + 0) * 72 + b_gs * 4;
  const int bw1 = (b_n + 1) * 72 + b_gs * 4;
  const int bw2 = (b_n + 2) * 72 + b_gs * 4;
  const int bw3 = (b_n + 3) * 72 + b_gs * 4;

  const int lane = tid & 63;
  const int wid = tid >> 6;
  const int wm = wid << 6;
  const int lr = lane & 15, lg = lane >> 4;

  int bbase[8], bslot[8];
#pragma unroll
  for (int j = 0; j < 8; ++j) {
    const int n = 16 * j + lr;
    bbase[j] = n * 72;
    bslot[j] = lg ^ ((n >> 3) & 7);
  }

  f32x4 acc[4][8];
#pragma unroll
  for (int i = 0; i < 4; ++i)
#pragma unroll
    for (int j = 0; j < 8; ++j) acc[i][j] = f32x4{0.f, 0.f, 0.f, 0.f};

  const unsigned short* ap0 = A16 + (size_t)(wm + lr) * K + k0 + 8 * lg;
  const unsigned short* ap1 = ap0 + (size_t)16 * K;
  const unsigned short* ap2 = ap0 + (size_t)32 * K;
  const unsigned short* ap3 = ap0 + (size_t)48 * K;
  const float* bp = B + (size_t)(k0 + b_g * 4) * N + n0 + b_n;

  float4 pb0, pb1, pb2, pb3;
  bf16x8 af[8];

#define LOAD_B()                                  \
  do {                                            \
    pb0 = *(const float4*)(bp);                   \
    pb1 = *(const float4*)(bp + N);               \
    pb2 = *(const float4*)(bp + 2 * (size_t)N);   \
    pb3 = *(const float4*)(bp + 3 * (size_t)N);   \
    bp += (size_t)64 * N;                         \
  } while (0)

#define LOAD_A0()                                 \
  do {                                            \
    af[0] = *(const bf16x8*)(ap0);                \
    af[1] = *(const bf16x8*)(ap1);                \
    af[2] = *(const bf16x8*)(ap2);                \
    af[3] = *(const bf16x8*)(ap3);                \
  } while (0)

#define LOAD_A1()                                 \
  do {                                            \
    af[4] = *(const bf16x8*)(ap0 + 32);           \
    af[5] = *(const bf16x8*)(ap1 + 32);           \
    af[6] = *(const bf16x8*)(ap2 + 32);           \
    af[7] = *(const bf16x8*)(ap3 + 32);           \
    ap0 += 64; ap1 += 64; ap2 += 64; ap3 += 64;   \
  } while (0)

#define WRITE_B(buf)                                           \
  do {                                                         \
    uint2 qv;                                                  \
    qv.x = pk2(pb0.x, pb1.x); qv.y = pk2(pb2.x, pb3.x);        \
    *(uint2*)(Bs[buf] + bw0) = qv;                             \
    qv.x = pk2(pb0.y, pb1.y); qv.y = pk2(pb2.y, pb3.y);        \
    *(uint2*)(Bs[buf] + bw1) = qv;                             \
    qv.x = pk2(pb0.z, pb1.z); qv.y = pk2(pb2.z, pb3.z);        \
    *(uint2*)(Bs[buf] + bw2) = qv;                             \
    qv.x = pk2(pb0.w, pb1.w); qv.y = pk2(pb2.w, pb3.w);        \
    *(uint2*)(Bs[buf] + bw3) = qv;                             \
  } while (0)

  const int nsteps = Kp >> 6;
  LOAD_B();
  LOAD_A0();
  LOAD_A1();
  WRITE_B(0);
  LOAD_B();
  asm volatile("s_waitcnt lgkmcnt(0)" ::: "memory");
  __builtin_amdgcn_s_barrier();

  for (int t = 0; t < nsteps; ++t) {
    const int buf = t & 1;
    if (t + 1 < nsteps) { WRITE_B(buf ^ 1); }
    if (t + 2 < nsteps) { LOAD_B(); }
    {
      bf16x8 bfr[8];
#pragma unroll
      for (int j = 0; j < 8; ++j)
        bfr[j] = *(const bf16x8*)(Bs[buf] + bbase[j] + 8 * bslot[j]);
#pragma unroll
      for (int i = 0; i < 4; ++i)
#pragma unroll
        for (int j = 0; j < 8; ++j)
          acc[i][j] = __builtin_amdgcn_mfma_f32_16x16x32_bf16(
              af[i], bfr[j], acc[i][j], 0, 0, 0);
    }
    if (t + 1 < nsteps) { LOAD_A0(); }
    {
      bf16x8 bfr[8];
#pragma unroll
      for (int j = 0; j < 8; ++j)
        bfr[j] = *(const bf16x8*)(Bs[buf] + bbase[j] + 8 * (bslot[j] ^ 4));
#pragma unroll
      for (int i = 0; i < 4; ++i)
#pragma unroll
        for (int j = 0; j < 8; ++j)
          acc[i][j] = __builtin_amdgcn_mfma_f32_16x16x32_bf16(
              af[4 + i], bfr[j], acc[i][j], 0, 0, 0);
    }
    if (t + 1 < nsteps) { LOAD_A1(); }
    asm volatile("s_waitcnt lgkmcnt(0)" ::: "memory");
    __builtin_amdgcn_s_barrier();
  }
#undef LOAD_B
#undef LOAD_A0
#undef LOAD_A1
#undef WRITE_B
  float* Cp = (PARTS > 1) ? (C + (size_t)blockIdx.y * 512 * (size_t)N) : C;
#pragma unroll
  for (int j = 0; j < 8; ++j) {
    const long col = n0 + 16 * j + lr;
    const float bv = (PARTS == 1 && bias) ? bias[col] : 0.f;
#pragma unroll
    for (int i = 0; i < 4; ++i) {
      const long row = wm + 16 * i + (lg << 2);
#pragma unroll
      for (int r = 0; r < 4; ++r) {
        float x = acc[i][j][r] + bv;
        if (PARTS == 1 && ACT == 1) x = tanhf(x);
        Cp[(row + r) * N + col] = x;
      }
    }
  }
}

// ---------------- split-K reduce: dst = act(sum_p P[p] + bias), bf16 out ----------------
template <int ACT, int PARTS>
__global__ __launch_bounds__(256) void reduce_parts_b(
    const float* __restrict__ P, const float* __restrict__ bias,
    unsigned short* __restrict__ dst, int N) {
  const int col = blockIdx.x * 256 + threadIdx.x;
  const int row = blockIdx.y;
  const size_t MN = (size_t)512 * N;
  const size_t idx = (size_t)row * N + col;
  float s = bias[col];
#pragma unroll
  for (int p = 0; p < PARTS; ++p) s += P[p * MN + idx];
  dst[idx] = f2b((ACT == 1) ? tanhf(s) : s);
}

// ---------------- row softmax, in place, 2-pass online ----------------
__global__ __launch_bounds__(256) void softmax_rows(float* __restrict__ x) {
  const int b = blockIdx.x;
  float* row = x + (size_t)b * V_DIM;
  const int tid = threadIdx.x;
  const int lane = tid & 63, w = tid >> 6;
  __shared__ float sm[4], sl[4];
  const float4* r4 = (const float4*)row;
  float m = -3.4e38f, l = 0.f;
  for (int i = tid; i < V_DIM / 4; i += 256) {
    float4 v = r4[i];
    float cm = fmaxf(fmaxf(v.x, v.y), fmaxf(v.z, v.w));
    if (cm > m) { l *= __expf(m - cm); m = cm; }
    l += __expf(v.x - m) + __expf(v.y - m) + __expf(v.z - m) + __expf(v.w - m);
  }
#pragma unroll
  for (int o = 32; o; o >>= 1) {
    float om = __shfl_xor(m, o, 64);
    float ol = __shfl_xor(l, o, 64);
    float nm = fmaxf(m, om);
    l = l * __expf(m - nm) + ol * __expf(om - nm);
    m = nm;
  }
  if (lane == 0) { sm[w] = m; sl[w] = l; }
  __syncthreads();
  float M = fmaxf(fmaxf(sm[0], sm[1]), fmaxf(sm[2], sm[3]));
  float L = sl[0] * __expf(sm[0] - M) + sl[1] * __expf(sm[1] - M) +
            sl[2] * __expf(sm[2] - M) + sl[3] * __expf(sm[3] - M);
  const float inv = 1.f / L;
  float4* w4p = (float4*)row;
  for (int i = tid; i < V_DIM / 4; i += 256) {
    float4 v = r4[i];
    float4 o4;
    o4.x = __expf(v.x - M) * inv;
    o4.y = __expf(v.y - M) * inv;
    o4.z = __expf(v.z - M) * inv;
    o4.w = __expf(v.w - M) * inv;
    w4p[i] = o4;
  }
}

extern "C" void kernel_launch(void* const* d_in, const int* in_sizes, int n_in,
                              void* d_out, int out_size, void* d_ws, size_t ws_size,
                              hipStream_t stream) {
  const float* y      = (const float*)d_in[0];
  const float* state  = (const float*)d_in[1];
  const float* encode = (const float*)d_in[2];
  const float* aW1    = (const float*)d_in[3];
  const float* aW2    = (const float*)d_in[4];
  const float* aW3    = (const float*)d_in[5];
  const float* gk     = (const float*)d_in[6];
  const float* grk    = (const float*)d_in[7];
  const float* gb     = (const float*)d_in[8];
  const float* w1     = (const float*)d_in[9];
  const float* b1     = (const float*)d_in[10];
  const float* w2     = (const float*)d_in[11];
  const float* b2     = (const float*)d_in[12];
  const float* w3     = (const float*)d_in[13];
  const float* b3     = (const float*)d_in[14];
  float* out = (float*)d_out;
  float* ws = (float*)d_ws;

  float* ctx = ws;                            // 262144 f32
  float* X0  = ws + 262144;                   // 4 x 2359296 f32 (Xall partials)
  float* R0  = ws + 9699328;                  // 4 x 786432 f32 (R partials)
  float* hg1 = ws + 12845056;                 // 262144 f32
  float* hg2 = ws + 13107200;                 // 262144 f32
  unsigned short* gb16 = (unsigned short*)(ws + 13369344);  // 512*1536 bf16
  unsigned short* dd1b = (unsigned short*)(ws + 13762560);  // 512*5120 bf16
  unsigned short* dd2b = (unsigned short*)(ws + 15073280);  // 512*5120 bf16

  float* g_out = out;                               // [512, 32000]
  float* h3 = out + (size_t)B_DIM * V_DIM;          // new_state [512, 512]
  float* P = out;  // split-K partials in not-yet-written logits region
                   // (max 6 * 512*5120 f32 = 63 MB < 65.5 MB)

  const float* bi = gb;
  const float* br = gb + 1536;

  attn_kernel<<<512, 256, 0, stream>>>(state, encode, aW1, aW2, aW3, ctx);
  // Xall = [state;ctx;y] @ gk (seq-stack fused), split-K=4
  gemm_k<4><<<dim3(12 * 12, 4), 256, 0, stream>>>(state, ctx, y, gk, X0, 1536, 1536, 512);
  gru_gate<4, 0><<<1024, 256, 0, stream>>>(X0, bi, nullptr, br, nullptr, hg1);
  gemm_k<4><<<dim3(4 * 12, 4), 256, 0, stream>>>(hg1, hg1, hg1, grk, R0, 512, 1536, 512);
  gru_gate<4, 4><<<1024, 256, 0, stream>>>(X0 + 786432, bi, R0, br, hg1, hg2);
  gemm_k<4><<<dim3(4 * 12, 4), 256, 0, stream>>>(hg2, hg2, hg2, grk, R0, 512, 1536, 512);
  gru_gate<4, 4><<<1024, 256, 0, stream>>>(X0 + 1572864, bi, R0, br, hg2, h3);
  // g = [y | ctx | new_state] as bf16
  pack3b<<<dim3(1024, 3), 256, 0, stream>>>(y, ctx, h3, gb16);
  // h1 = tanh(g@w1+b1): 128-panel, split-K=6
  gemm_pn<0, 6><<<dim3(40, 6), 512, 0, stream>>>(gb16, w1, nullptr, P, H_DIM, 1536);
  reduce_parts_b<1, 6><<<dim3(20, 512), 256, 0, stream>>>(P, b1, dd1b, H_DIM);
  // h2 = tanh(h1@w2+b2): 128-panel, split-K=5
  gemm_pn<0, 5><<<dim3(40, 5), 512, 0, stream>>>(dd1b, w2, nullptr, P, H_DIM, H_DIM);
  reduce_parts_b<1, 5><<<dim3(20, 512), 256, 0, stream>>>(P, b2, dd2b, H_DIM);
  // logits = h2@w3+b3: 128-col panels, 250 blocks (w3 read once, 80 steps)
  gemm_pn<0, 1><<<dim3(250, 1), 512, 0, stream>>>(dd2b, w3, b3, g_out, V_DIM, H_DIM);
  softmax_rows<<<512, 256, 0, stream>>>(g_out);
}